// Round 5
// baseline (1231.008 us; speedup 1.0000x reference)
//
#include <hip/hip_runtime.h>
#include <hip/hip_bf16.h>

#define N_NODESC 50000
#define N_EDGESC 800000
#define DD 128
#define HH 8
#define HDIM 16
#define N_NT 3
#define N_ET 5

// ---------------- workspace layout (bytes), total ~88.5 MB ----------------
#define K8_OFF     ((size_t)0)           // fp8 [N][128] 6.4 MB (dead after edgeagg)
#define V8_OFF     ((size_t)6400000)     // fp8 [N][128] 6.4 MB (dead after edgeagg)
#define QT8_OFF    ((size_t)12800000)    // fp8 [N][640] 32 MB (dead after edgeagg)
#define XP_OFF     ((size_t)44800000)    // bf16 [N][128] permuted 12.8 MB (dead after proj)
#define T_OFF      ((size_t)0)           // bf16 [N][512] 51.2 MB overlays K8|V8|Qt8|Xp (all dead at ffn1)
#define AGG_OFF    ((size_t)57600000)    // bf16 [N][128] 12.8 MB
#define H1B_OFF    ((size_t)70400000)    // bf16 [N][128] 12.8 MB
#define WOUTT_OFF  ((size_t)83200000)    // bf16 [128][128] 32 KB
#define W1T_OFF    ((size_t)83232768)    // bf16 [512][128] 128 KB
#define W2T_OFF    ((size_t)83363840)    // bf16 [128][512] 128 KB
#define WC_OFF     ((size_t)83494912)    // f32 [5][3][8][16][16] 120 KB
#define WALL_OFF   ((size_t)83617792)    // bf16 [3][896][128] 672 KB
#define EDATA_OFF  ((size_t)84305920)    // int [E] packed src|et<<16, 3.2 MB
#define ROWS_OFF   ((size_t)87505920)    // int [N+1] (+pad)
#define ORIG_OFF   ((size_t)87705984)    // int [N] origof
#define NEWOF_OFF  ((size_t)87905984)    // int [N]
#define DEG_OFF    ((size_t)88105984)    // int [N] -- start of zeroed region
#define CUR_OFF    ((size_t)88305984)    // int [N]
#define TCNT_OFF   ((size_t)88505984)    // int [4]
#define TCUR_OFF   ((size_t)88506000)    // int [4] -- end of zeroed region
#define TOFS_OFF   ((size_t)88506016)    // int [4] (fully written by tscan)

using short8 = __attribute__((ext_vector_type(8))) short;
using f32x4  = __attribute__((ext_vector_type(4))) float;

__device__ __forceinline__ ushort f2b(float f) {
    __hip_bfloat16 h = __float2bfloat16(f);
    return *(ushort*)&h;
}
__device__ __forceinline__ float b2f(ushort u) {
    __hip_bfloat16 h = *(__hip_bfloat16*)&u;
    return __bfloat162float(h);
}

// ---- combined Q-side weights: Wc[et][t][h][c][d] = 64*mu[h,et]*sum_f WQ[t,h,c,f]*We[et,h,d,f]
// 64 = 256 (Qt fp8 scale) * 0.25 (1/sqrt(HD)); with K scaled x4, exp arg = p/1024.
__global__ __launch_bounds__(256) void wc_kernel(
    const float* __restrict__ WQ, const float* __restrict__ We,
    const float* __restrict__ mu, float* __restrict__ Wc)
{
    const int et = blockIdx.x, t = blockIdx.y, h = blockIdx.z;
    const int c = threadIdx.x >> 4, dd = threadIdx.x & 15;
    const float* wq = WQ + (((t * HH + h) * HDIM + c) * HDIM);
    const float* we = We + (((et * HH + h) * HDIM + dd) * HDIM);
    float s = 0.f;
#pragma unroll
    for (int f = 0; f < 16; f++) s = fmaf(wq[f], we[f], s);
    Wc[((((et * N_NT + t) * HH + h) * HDIM + c) * HDIM) + dd] = 64.f * mu[h * N_ET + et] * s;
}

// ---- Wall[t][c][k] bf16: block-diag-per-head combined projection [4K | 4V | Qt(et=0..4)]
__global__ __launch_bounds__(256) void wall_kernel(
    const float* __restrict__ Wk, const float* __restrict__ Wv,
    const float* __restrict__ Wc, ushort* __restrict__ Wall)
{
    const int gid = blockIdx.x * 256 + threadIdx.x;
    if (gid >= N_NT * 896 * 128) return;
    const int t = gid / (896 * 128);
    const int rem = gid % (896 * 128);
    const int c = rem / 128, k = rem % 128;
    const int hk = k >> 4, ck = k & 15;
    float v = 0.f;
    if (c < 128) {
        const int hc = c >> 4, j = c & 15;
        if (hk == hc) v = 4.f * Wk[((t * HH + hc) * HDIM + ck) * HDIM + j];
    } else if (c < 256) {
        const int c2 = c - 128, hc = c2 >> 4, j = c2 & 15;
        if (hk == hc) v = 4.f * Wv[((t * HH + hc) * HDIM + ck) * HDIM + j];
    } else {
        const int cq = c - 256, et = cq >> 7, dd = cq & 127;
        const int hq = dd >> 4, j = dd & 15;
        if (hk == hq) v = Wc[((((et * N_NT + t) * HH + hq) * HDIM + ck) * HDIM) + j];
    }
    Wall[gid] = f2b(v);
}

// ---------------- node-type sort (permutation) ----------------
__global__ void tcount_kernel(const int* __restrict__ ntype, int* __restrict__ tcnt) {
    const int n = blockIdx.x * 256 + threadIdx.x;
    if (n < N_NODESC) atomicAdd(&tcnt[ntype[n]], 1);
}
__global__ void tscan_kernel(const int* __restrict__ tcnt, int* __restrict__ tofs) {
    tofs[0] = 0;
    tofs[1] = tcnt[0];
    tofs[2] = tcnt[0] + tcnt[1];
    tofs[3] = N_NODESC;
}
__global__ void tscatter_kernel(const int* __restrict__ ntype, const int* __restrict__ tofs,
                                int* __restrict__ tcur, int* __restrict__ origof,
                                int* __restrict__ newof) {
    const int n = blockIdx.x * 256 + threadIdx.x;
    if (n < N_NODESC) {
        const int t = ntype[n];
        const int p = tofs[t] + atomicAdd(&tcur[t], 1);
        origof[p] = n;
        newof[n] = p;
    }
}

// ---- Xp[newof[n]] = bf16(x[n]) ----
__global__ __launch_bounds__(256) void xb_kernel(
    const float* __restrict__ x, const int* __restrict__ newof, ushort* __restrict__ Xp)
{
    const int gid = blockIdx.x * 256 + threadIdx.x;
    if (gid >= N_NODESC * 32) return;
    const int n = gid >> 5, c = (gid & 31) * 4;
    const float4 v = *(const float4*)(x + (size_t)n * DD + c);
    ushort o[4] = {f2b(v.x), f2b(v.y), f2b(v.z), f2b(v.w)};
    const int p = newof[n];
    *(uint2*)(Xp + (size_t)p * DD + c) = *(uint2*)o;
}

// ---------------- CSR build (on permuted ids) ----------------
__global__ void deg_kernel(const int* __restrict__ dst, const int* __restrict__ newof,
                           int* __restrict__ deg) {
    const int e = blockIdx.x * 256 + threadIdx.x;
    if (e < N_EDGESC) atomicAdd(&deg[newof[dst[e]]], 1);
}

__global__ __launch_bounds__(1024) void scan_kernel(
    const int* __restrict__ deg, int* __restrict__ rowstart)
{
    __shared__ int part[1024];
    const int tid = threadIdx.x;
    const int per = 49;
    const int base = tid * per;
    int s = 0;
    for (int i = 0; i < per; i++) { int idx = base + i; if (idx < N_NODESC) s += deg[idx]; }
    part[tid] = s;
    __syncthreads();
    for (int off = 1; off < 1024; off <<= 1) {
        int v = (tid >= off) ? part[tid - off] : 0;
        __syncthreads();
        part[tid] += v;
        __syncthreads();
    }
    int run = (tid == 0) ? 0 : part[tid - 1];
    for (int i = 0; i < per; i++) {
        int idx = base + i;
        if (idx < N_NODESC) { rowstart[idx] = run; run += deg[idx]; }
    }
    if (tid == 1023) rowstart[N_NODESC] = part[1023];
}

__global__ void fill_kernel(const int* __restrict__ src, const int* __restrict__ dst,
                            const int* __restrict__ etype, const int* __restrict__ newof,
                            const int* __restrict__ rowstart,
                            int* __restrict__ cursor, int* __restrict__ edata) {
    const int e = blockIdx.x * 256 + threadIdx.x;
    if (e < N_EDGESC) {
        const int nd = newof[dst[e]];
        const int p = atomicAdd(&cursor[nd], 1);
        edata[rowstart[nd] + p] = newof[src[e]] | (etype[e] << 16);
    }
}

// ---------------- projection GEMM: Xp @ Wall[t] -> K8 | V8 | Qt8 (fp8) ----------------
#define LDP 40

__global__ __launch_bounds__(256) void proj_gemm(
    const ushort* __restrict__ Xp, const ushort* __restrict__ Wall,
    const int* __restrict__ tofs,
    unsigned char* __restrict__ K8, unsigned char* __restrict__ V8,
    unsigned char* __restrict__ Qt8)
{
    const int t = blockIdx.z;
    const int rs = tofs[t], re = tofs[t + 1];
    const int mBase = rs + blockIdx.x * 128;
    if (mBase >= re) return;
    const int nBase = blockIdx.y * 128;
    const ushort* Bt = Wall + (size_t)t * 896 * 128;

    __shared__ ushort As[128 * LDP];
    __shared__ ushort Bs[128 * LDP];
    const int tid = threadIdx.x;
    const int lane = tid & 63, wave = tid >> 6;
    const int mw = (wave >> 1) * 64, nw = (wave & 1) * 64;
    const int l15 = lane & 15, q8 = (lane >> 4) * 8;

    f32x4 acc[4][4];
#pragma unroll
    for (int i = 0; i < 4; i++)
#pragma unroll
        for (int j = 0; j < 4; j++) acc[i][j] = (f32x4){0.f, 0.f, 0.f, 0.f};

    const int r0 = tid >> 2, c0 = (tid & 3) * 8;
    int rA0 = mBase + r0;      if (rA0 >= N_NODESC) rA0 = N_NODESC - 1;
    int rA1 = mBase + r0 + 64; if (rA1 >= N_NODESC) rA1 = N_NODESC - 1;

    for (int kk = 0; kk < 128; kk += 32) {
        short8 a0 = *(const short8*)(Xp + (size_t)rA0 * DD + kk + c0);
        short8 a1 = *(const short8*)(Xp + (size_t)rA1 * DD + kk + c0);
        short8 b0 = *(const short8*)(Bt + (size_t)(nBase + r0) * 128 + kk + c0);
        short8 b1 = *(const short8*)(Bt + (size_t)(nBase + r0 + 64) * 128 + kk + c0);
        *(short8*)&As[r0 * LDP + c0] = a0;
        *(short8*)&As[(r0 + 64) * LDP + c0] = a1;
        *(short8*)&Bs[r0 * LDP + c0] = b0;
        *(short8*)&Bs[(r0 + 64) * LDP + c0] = b1;
        __syncthreads();
        short8 af[4], bf[4];
#pragma unroll
        for (int i = 0; i < 4; i++)
            af[i] = *(const short8*)&As[(mw + i * 16 + l15) * LDP + q8];
#pragma unroll
        for (int j = 0; j < 4; j++)
            bf[j] = *(const short8*)&Bs[(nw + j * 16 + l15) * LDP + q8];
#pragma unroll
        for (int i = 0; i < 4; i++)
#pragma unroll
            for (int j = 0; j < 4; j++)
                acc[i][j] = __builtin_amdgcn_mfma_f32_16x16x32_bf16(af[i], bf[j], acc[i][j], 0, 0, 0);
        __syncthreads();
    }

    const int rq = (lane >> 4) * 4;
#pragma unroll
    for (int i = 0; i < 4; i++) {
#pragma unroll
        for (int r = 0; r < 4; r++) {
            const int gm = mBase + mw + i * 16 + rq + r;
            if (gm >= re) continue;
#pragma unroll
            for (int j = 0; j < 4; j++) {
                const int gn = nBase + nw + j * 16 + l15;
                const float v = acc[i][j][r];
                const unsigned char b8 =
                    (unsigned char)(__builtin_amdgcn_cvt_pk_fp8_f32(v, v, 0, false) & 0xff);
                if (gn < 128)      K8[(size_t)gm * 128 + gn] = b8;
                else if (gn < 256) V8[(size_t)gm * 128 + (gn - 128)] = b8;
                else               Qt8[(size_t)gm * 640 + (gn - 256)] = b8;
            }
        }
    }
}

// ---------------- fused edge pass (fp8 gathers, permuted ids) ----------------
#define PROC(ed) { \
    const int s_ = (ed) & 0xffff; \
    const int et_ = (ed) >> 16; \
    const float k_ = __builtin_amdgcn_cvt_f32_fp8((int)K8[(size_t)s_ * 128 + f], 0); \
    const float v_ = __builtin_amdgcn_cvt_f32_fp8((int)V8[(size_t)s_ * 128 + f], 0); \
    const float qv_ = (et_ == 0) ? q0 : (et_ == 1) ? q1 : (et_ == 2) ? q2 : (et_ == 3) ? q3 : q4; \
    float p_ = qv_ * k_; \
    p_ += __shfl_xor(p_, 1); p_ += __shfl_xor(p_, 2); \
    p_ += __shfl_xor(p_, 4); p_ += __shfl_xor(p_, 8); \
    const float ex_ = __expf(p_ * (1.0f / 1024.0f)); \
    den += ex_; acc = fmaf(ex_, v_, acc); }

__global__ __launch_bounds__(128) void edgeagg_kernel(
    const int* __restrict__ rowstart, const int* __restrict__ edata,
    const unsigned char* __restrict__ Qt8,
    const unsigned char* __restrict__ K8, const unsigned char* __restrict__ V8,
    const int* __restrict__ origof, ushort* __restrict__ agg)
{
    const int n = blockIdx.x;
    const int f = threadIdx.x;
    const float q0 = __builtin_amdgcn_cvt_f32_fp8((int)Qt8[(size_t)n * 640 + 0 * 128 + f], 0);
    const float q1 = __builtin_amdgcn_cvt_f32_fp8((int)Qt8[(size_t)n * 640 + 1 * 128 + f], 0);
    const float q2 = __builtin_amdgcn_cvt_f32_fp8((int)Qt8[(size_t)n * 640 + 2 * 128 + f], 0);
    const float q3 = __builtin_amdgcn_cvt_f32_fp8((int)Qt8[(size_t)n * 640 + 3 * 128 + f], 0);
    const float q4 = __builtin_amdgcn_cvt_f32_fp8((int)Qt8[(size_t)n * 640 + 4 * 128 + f], 0);

    const int s0 = rowstart[n], s1 = rowstart[n + 1];
    float acc = 0.f, den = 0.f;
    int i = s0;
    for (; i + 3 < s1; i += 4) {
        const int e0 = edata[i], e1 = edata[i + 1], e2 = edata[i + 2], e3 = edata[i + 3];
        PROC(e0); PROC(e1); PROC(e2); PROC(e3);
    }
    for (; i < s1; i++) { const int e0 = edata[i]; PROC(e0); }
    // undo V scale (x4): 0.25
    agg[(size_t)origof[n] * DD + f] = f2b(0.25f * acc / (den + 1e-10f));
}

// ---- weight transposes to bf16 [N][K] for MFMA B-operand ----
__global__ __launch_bounds__(256) void convert_wt(
    const float* __restrict__ Wout, const float* __restrict__ W1, const float* __restrict__ W2,
    ushort* __restrict__ Woutt, ushort* __restrict__ W1t, ushort* __restrict__ W2t)
{
    const int gid = blockIdx.x * 256 + threadIdx.x;
    if (gid < 16384) {
        const int nn = gid >> 7, k = gid & 127;
        Woutt[gid] = f2b(Wout[k * 128 + nn]);
    } else if (gid < 16384 + 65536) {
        const int i = gid - 16384;
        const int nn = i >> 7, k = i & 127;
        W1t[i] = f2b(W1[k * 512 + nn]);
    } else if (gid < 16384 + 131072) {
        const int i = gid - 81920;
        const int nn = i >> 9, k = i & 511;
        W2t[i] = f2b(W2[k * 128 + nn]);
    }
}

// ---------------- MFMA bf16 GEMM 128x128 tile, BK=32, fused epilogues ----------------
// EPI 0: T = bf16 gelu(acc + bias)                (ffn1, grid.y = N/128)
// EPI 1: h1b = bf16 LN(acc + bias + residF)       (attn out)
// EPI 2: out = f32 LN(acc + bias + b2f(residB))   (ffn2)
template<int KT, int EPI>
__global__ __launch_bounds__(256) void mfma_gemm(
    const ushort* __restrict__ A, const ushort* __restrict__ Bt,
    const float* __restrict__ bias,
    const float* __restrict__ residF, const ushort* __restrict__ residB,
    const float* __restrict__ g, const float* __restrict__ b,
    float* __restrict__ outF, ushort* __restrict__ outB, int ldOut)
{
    __shared__ ushort As[128 * LDP];
    __shared__ ushort Bs[128 * LDP];
    __shared__ float red[2][2][128];
    const int tid = threadIdx.x;
    const int lane = tid & 63, wave = tid >> 6;
    const int mw = (wave >> 1) * 64, nw = (wave & 1) * 64;
    const int mBase = blockIdx.x * 128, nBase = blockIdx.y * 128;
    const int l15 = lane & 15, q8 = (lane >> 4) * 8;

    f32x4 acc[4][4];
#pragma unroll
    for (int i = 0; i < 4; i++)
#pragma unroll
        for (int j = 0; j < 4; j++) acc[i][j] = (f32x4){0.f, 0.f, 0.f, 0.f};

    const int r0 = tid >> 2;
    const int c0 = (tid & 3) * 8;

    for (int kk = 0; kk < KT; kk += 32) {
        const ushort* pa = A  + (size_t)(mBase + r0) * KT + kk + c0;
        const ushort* pb = Bt + (size_t)(nBase + r0) * KT + kk + c0;
        short8 a0 = *(const short8*)pa;
        short8 a1 = *(const short8*)(pa + (size_t)64 * KT);
        short8 b0 = *(const short8*)pb;
        short8 b1 = *(const short8*)(pb + (size_t)64 * KT);
        *(short8*)&As[r0 * LDP + c0] = a0;
        *(short8*)&As[(r0 + 64) * LDP + c0] = a1;
        *(short8*)&Bs[r0 * LDP + c0] = b0;
        *(short8*)&Bs[(r0 + 64) * LDP + c0] = b1;
        __syncthreads();

        short8 af[4], bf[4];
#pragma unroll
        for (int i = 0; i < 4; i++)
            af[i] = *(const short8*)&As[(mw + i * 16 + l15) * LDP + q8];
#pragma unroll
        for (int j = 0; j < 4; j++)
            bf[j] = *(const short8*)&Bs[(nw + j * 16 + l15) * LDP + q8];
#pragma unroll
        for (int i = 0; i < 4; i++)
#pragma unroll
            for (int j = 0; j < 4; j++)
                acc[i][j] = __builtin_amdgcn_mfma_f32_16x16x32_bf16(af[i], bf[j], acc[i][j], 0, 0, 0);
        __syncthreads();
    }

    const int rq = (lane >> 4) * 4;

    if (EPI == 0) {
#pragma unroll
        for (int i = 0; i < 4; i++) {
#pragma unroll
            for (int r = 0; r < 4; r++) {
                const int gm = mBase + mw + i * 16 + rq + r;
                if (gm >= N_NODESC) continue;
#pragma unroll
                for (int j = 0; j < 4; j++) {
                    const int gn = nBase + nw + j * 16 + l15;
                    float v = acc[i][j][r] + bias[gn];
                    v = 0.5f * v * (1.f + erff(v * 0.70710678118654752f));
                    outB[(size_t)gm * ldOut + gn] = f2b(v);
                }
            }
        }
    } else {
        float biasv[4], gv[4], bv[4];
#pragma unroll
        for (int j = 0; j < 4; j++) {
            const int gn = nw + j * 16 + l15;
            biasv[j] = bias[gn]; gv[j] = g[gn]; bv[j] = b[gn];
        }
#pragma unroll
        for (int i = 0; i < 4; i++) {
#pragma unroll
            for (int r = 0; r < 4; r++) {
                const int row = mw + i * 16 + rq + r;
                const int gm = mBase + row;
                float s = 0.f, ss = 0.f;
#pragma unroll
                for (int j = 0; j < 4; j++) {
                    const int gn = nw + j * 16 + l15;
                    float v = acc[i][j][r] + biasv[j];
                    if (EPI == 1) v += (gm < N_NODESC) ? residF[(size_t)gm * DD + gn] : 0.f;
                    else          v += (gm < N_NODESC) ? b2f(residB[(size_t)gm * DD + gn]) : 0.f;
                    acc[i][j][r] = v;
                    s += v; ss += v * v;
                }
                s  += __shfl_xor(s, 1);  s  += __shfl_xor(s, 2);  s  += __shfl_xor(s, 4);  s  += __shfl_xor(s, 8);
                ss += __shfl_xor(ss, 1); ss += __shfl_xor(ss, 2); ss += __shfl_xor(ss, 4); ss += __shfl_xor(ss, 8);
                if (l15 == 0) { red[0][nw >> 6][row] = s; red[1][nw >> 6][row] = ss; }
            }
        }
        __syncthreads();
#pragma unroll
        for (int i = 0; i < 4; i++) {
#pragma unroll
            for (int r = 0; r < 4; r++) {
                const int row = mw + i * 16 + rq + r;
                const int gm = mBase + row;
                if (gm >= N_NODESC) continue;
                const float s  = red[0][0][row] + red[0][1][row];
                const float ss = red[1][0][row] + red[1][1][row];
                const float mean = s * (1.f / 128.f);
                const float var  = ss * (1.f / 128.f) - mean * mean;
                const float rstd = rsqrtf(var + 1e-5f);
#pragma unroll
                for (int j = 0; j < 4; j++) {
                    const int gn = nw + j * 16 + l15;
                    const float o = (acc[i][j][r] - mean) * rstd * gv[j] + bv[j];
                    if (EPI == 1) outB[(size_t)gm * DD + gn] = f2b(o);
                    else          outF[(size_t)gm * DD + gn] = o;
                }
            }
        }
    }
}

extern "C" void kernel_launch(void* const* d_in, const int* in_sizes, int n_in,
                              void* d_out, int out_size, void* d_ws, size_t ws_size,
                              hipStream_t stream)
{
    const float* x     = (const float*)d_in[0];
    const int*   ei    = (const int*)d_in[1];
    const int*   etyp  = (const int*)d_in[2];
    const int*   ntype = (const int*)d_in[3];
    const float* Wq    = (const float*)d_in[4];
    const float* Wk    = (const float*)d_in[5];
    const float* Wv    = (const float*)d_in[6];
    const float* We    = (const float*)d_in[7];
    const float* mu    = (const float*)d_in[8];
    const float* Wout  = (const float*)d_in[9];
    const float* bout  = (const float*)d_in[10];
    const float* g1    = (const float*)d_in[11];
    const float* b1ln  = (const float*)d_in[12];
    const float* W1    = (const float*)d_in[13];
    const float* b1    = (const float*)d_in[14];
    const float* W2    = (const float*)d_in[15];
    const float* b2    = (const float*)d_in[16];
    const float* g2    = (const float*)d_in[17];
    const float* b2ln  = (const float*)d_in[18];
    float* out = (float*)d_out;

    char* ws = (char*)d_ws;
    unsigned char* K8    = (unsigned char*)(ws + K8_OFF);
    unsigned char* V8    = (unsigned char*)(ws + V8_OFF);
    unsigned char* Qt8   = (unsigned char*)(ws + QT8_OFF);
    ushort*        Xp    = (ushort*)(ws + XP_OFF);
    ushort*        T     = (ushort*)(ws + T_OFF);
    ushort*        agg   = (ushort*)(ws + AGG_OFF);
    ushort*        h1b   = (ushort*)(ws + H1B_OFF);
    ushort*        Woutt = (ushort*)(ws + WOUTT_OFF);
    ushort*        W1t   = (ushort*)(ws + W1T_OFF);
    ushort*        W2t   = (ushort*)(ws + W2T_OFF);
    float*         Wc    = (float*)(ws + WC_OFF);
    ushort*        Wall  = (ushort*)(ws + WALL_OFF);
    int*           edata = (int*)(ws + EDATA_OFF);
    int*           rows  = (int*)(ws + ROWS_OFF);
    int*           origof= (int*)(ws + ORIG_OFF);
    int*           newof = (int*)(ws + NEWOF_OFF);
    int*           deg   = (int*)(ws + DEG_OFF);
    int*           cur   = (int*)(ws + CUR_OFF);
    int*           tcnt  = (int*)(ws + TCNT_OFF);
    int*           tcur  = (int*)(ws + TCUR_OFF);
    int*           tofs  = (int*)(ws + TOFS_OFF);

    const int* srcA = ei;
    const int* dstA = ei + N_EDGESC;

    // zero deg + cur + tcnt + tcur (contiguous)
    (void)hipMemsetAsync(ws + DEG_OFF, 0, 400032, stream);

    convert_wt<<<576, 256, 0, stream>>>(Wout, W1, W2, Woutt, W1t, W2t);
    wc_kernel<<<dim3(N_ET, N_NT, HH), 256, 0, stream>>>(Wq, We, mu, Wc);
    wall_kernel<<<1344, 256, 0, stream>>>(Wk, Wv, Wc, Wall);

    tcount_kernel<<<196, 256, 0, stream>>>(ntype, tcnt);
    tscan_kernel<<<1, 1, 0, stream>>>(tcnt, tofs);
    tscatter_kernel<<<196, 256, 0, stream>>>(ntype, tofs, tcur, origof, newof);
    xb_kernel<<<6250, 256, 0, stream>>>(x, newof, Xp);

    deg_kernel<<<3125, 256, 0, stream>>>(dstA, newof, deg);
    scan_kernel<<<1, 1024, 0, stream>>>(deg, rows);
    fill_kernel<<<3125, 256, 0, stream>>>(srcA, dstA, etyp, newof, rows, cur, edata);

    proj_gemm<<<dim3(394, 7, 3), 256, 0, stream>>>(Xp, Wall, tofs, K8, V8, Qt8);
    edgeagg_kernel<<<N_NODESC, 128, 0, stream>>>(rows, edata, Qt8, K8, V8, origof, agg);

    // h1b = LN1(agg @ Wout + bout + x)  (bf16)
    mfma_gemm<128, 1><<<391, 256, 0, stream>>>(agg, Woutt, bout, x, nullptr, g1, b1ln, nullptr, h1b, 128);
    // T = gelu(h1b @ W1 + b1)  (bf16)
    mfma_gemm<128, 0><<<dim3(391, 4), 256, 0, stream>>>(h1b, W1t, b1, nullptr, nullptr, nullptr, nullptr, nullptr, T, 512);
    // out = LN2(T @ W2 + b2 + h1b)  (f32)
    mfma_gemm<512, 2><<<391, 256, 0, stream>>>(T, W2t, b2, nullptr, h1b, g2, b2ln, out, nullptr, 128);
}

// Round 6
// 571.980 us; speedup vs baseline: 2.1522x; 2.1522x over previous
//
#include <hip/hip_runtime.h>
#include <hip/hip_bf16.h>

#define N_NODESC 50000
#define N_EDGESC 800000
#define DD 128
#define HH 8
#define HDIM 16
#define N_NT 3
#define N_ET 5
#define NPB 196   // node blocks for permutation (196*256 >= 50000)

// ---------------- workspace layout (bytes), total ~88.5 MB ----------------
#define K8_OFF     ((size_t)0)           // fp8 [N][128] 6.4 MB (dead after edgeagg)
#define V8_OFF     ((size_t)6400000)     // fp8 [N][128] 6.4 MB (dead after edgeagg)
#define QT8_OFF    ((size_t)12800000)    // fp8 [N][640] 32 MB (dead after edgeagg)
#define XP_OFF     ((size_t)44800000)    // bf16 [N][128] permuted 12.8 MB (dead after proj)
#define T_OFF      ((size_t)0)           // bf16 [N][512] 51.2 MB overlays K8|V8|Qt8|Xp (all dead at ffn1)
#define AGG_OFF    ((size_t)57600000)    // bf16 [N][128] 12.8 MB
#define H1B_OFF    ((size_t)70400000)    // bf16 [N][128] 12.8 MB
#define WOUTT_OFF  ((size_t)83200000)    // bf16 [128][128] 32 KB
#define W1T_OFF    ((size_t)83232768)    // bf16 [512][128] 128 KB
#define W2T_OFF    ((size_t)83363840)    // bf16 [128][512] 128 KB
#define WC_OFF     ((size_t)83494912)    // f32 [5][3][8][16][16] 120 KB
#define WALL_OFF   ((size_t)83617792)    // bf16 [3][896][128] 672 KB
#define EDATA_OFF  ((size_t)84305920)    // int [E] packed src|et<<16, 3.2 MB
#define ROWS_OFF   ((size_t)87505920)    // int [N+1] (+pad)
#define ORIG_OFF   ((size_t)87705984)    // int [N] origof
#define NEWOF_OFF  ((size_t)87905984)    // int [N]
#define DEG_OFF    ((size_t)88105984)    // int [N] -- start of zeroed region
#define CUR_OFF    ((size_t)88305984)    // int [N] -- end of zeroed region
#define TOFS_OFF   ((size_t)88505984)    // int [4]  (fully written by permscan)
#define BH_OFF     ((size_t)88506048)    // int [3*NPB] block hist, type-major (fully written)
#define BB_OFF     ((size_t)88508416)    // int [3*NPB] block bases (fully written)

using short8 = __attribute__((ext_vector_type(8))) short;
using f32x4  = __attribute__((ext_vector_type(4))) float;

__device__ __forceinline__ ushort f2b(float f) {
    __hip_bfloat16 h = __float2bfloat16(f);
    return *(ushort*)&h;
}
__device__ __forceinline__ float b2f(ushort u) {
    __hip_bfloat16 h = *(__hip_bfloat16*)&u;
    return __bfloat162float(h);
}

// ---- combined Q-side weights: Wc[et][t][h][c][d] = 64*mu[h,et]*sum_f WQ[t,h,c,f]*We[et,h,d,f]
// 64 = 256 (Qt fp8 scale) * 0.25 (1/sqrt(HD)); with K scaled x4, exp arg = p/1024.
__global__ __launch_bounds__(256) void wc_kernel(
    const float* __restrict__ WQ, const float* __restrict__ We,
    const float* __restrict__ mu, float* __restrict__ Wc)
{
    const int et = blockIdx.x, t = blockIdx.y, h = blockIdx.z;
    const int c = threadIdx.x >> 4, dd = threadIdx.x & 15;
    const float* wq = WQ + (((t * HH + h) * HDIM + c) * HDIM);
    const float* we = We + (((et * HH + h) * HDIM + dd) * HDIM);
    float s = 0.f;
#pragma unroll
    for (int f = 0; f < 16; f++) s = fmaf(wq[f], we[f], s);
    Wc[((((et * N_NT + t) * HH + h) * HDIM + c) * HDIM) + dd] = 64.f * mu[h * N_ET + et] * s;
}

// ---- Wall[t][c][k] bf16: block-diag-per-head combined projection [4K | 4V | Qt(et=0..4)]
__global__ __launch_bounds__(256) void wall_kernel(
    const float* __restrict__ Wk, const float* __restrict__ Wv,
    const float* __restrict__ Wc, ushort* __restrict__ Wall)
{
    const int gid = blockIdx.x * 256 + threadIdx.x;
    if (gid >= N_NT * 896 * 128) return;
    const int t = gid / (896 * 128);
    const int rem = gid % (896 * 128);
    const int c = rem / 128, k = rem % 128;
    const int hk = k >> 4, ck = k & 15;
    float v = 0.f;
    if (c < 128) {
        const int hc = c >> 4, j = c & 15;
        if (hk == hc) v = 4.f * Wk[((t * HH + hc) * HDIM + ck) * HDIM + j];
    } else if (c < 256) {
        const int c2 = c - 128, hc = c2 >> 4, j = c2 & 15;
        if (hk == hc) v = 4.f * Wv[((t * HH + hc) * HDIM + ck) * HDIM + j];
    } else {
        const int cq = c - 256, et = cq >> 7, dd = cq & 127;
        const int hq = dd >> 4, j = dd & 15;
        if (hk == hq) v = Wc[((((et * N_NT + t) * HH + hq) * HDIM + ck) * HDIM) + j];
    }
    Wall[gid] = f2b(v);
}

// ---------------- atomic-free node-type counting sort ----------------
// phase 1: per-block type histogram via ballots (type-major output bh[t*NPB+b])
__global__ __launch_bounds__(256) void phist_kernel(
    const int* __restrict__ ntype, int* __restrict__ bh)
{
    const int b = blockIdx.x, tid = threadIdx.x;
    const int wave = tid >> 6, lane = tid & 63;
    const int n = b * 256 + tid;
    const int t = (n < N_NODESC) ? ntype[n] : -1;
    const unsigned long long m0 = __ballot(t == 0);
    const unsigned long long m1 = __ballot(t == 1);
    const unsigned long long m2 = __ballot(t == 2);
    __shared__ int wcnt[4][3];
    if (lane == 0) {
        wcnt[wave][0] = (int)__popcll(m0);
        wcnt[wave][1] = (int)__popcll(m1);
        wcnt[wave][2] = (int)__popcll(m2);
    }
    __syncthreads();
    if (tid < 3)
        bh[tid * NPB + b] = wcnt[0][tid] + wcnt[1][tid] + wcnt[2][tid] + wcnt[3][tid];
}

// phase 2: exclusive scan of 3*NPB=588 entries (one 640-thread block) -> bases + tofs
__global__ __launch_bounds__(640) void permscan_kernel(
    const int* __restrict__ bh, int* __restrict__ bb, int* __restrict__ tofs)
{
    __shared__ int part[640];
    const int tid = threadIdx.x;
    part[tid] = (tid < 3 * NPB) ? bh[tid] : 0;
    __syncthreads();
    for (int off = 1; off < 640; off <<= 1) {
        const int u = (tid >= off) ? part[tid - off] : 0;
        __syncthreads();
        part[tid] += u;
        __syncthreads();
    }
    const int excl = (tid == 0) ? 0 : part[tid - 1];
    if (tid < 3 * NPB) bb[tid] = excl;
    if (tid == 0) { tofs[0] = 0; tofs[3] = N_NODESC; }
    if (tid == NPB) tofs[1] = excl;        // total of type 0
    if (tid == 2 * NPB) tofs[2] = excl;    // + type 1
}

// phase 3: stable scatter: rank = block base + wave prefix + lane prefix (ballot popcount)
__global__ __launch_bounds__(256) void pscatter_kernel(
    const int* __restrict__ ntype, const int* __restrict__ bb,
    int* __restrict__ origof, int* __restrict__ newof)
{
    const int b = blockIdx.x, tid = threadIdx.x;
    const int wave = tid >> 6, lane = tid & 63;
    const int n = b * 256 + tid;
    const int t = (n < N_NODESC) ? ntype[n] : -1;
    const unsigned long long m0 = __ballot(t == 0);
    const unsigned long long m1 = __ballot(t == 1);
    const unsigned long long m2 = __ballot(t == 2);
    __shared__ int wcnt[4][3];
    if (lane == 0) {
        wcnt[wave][0] = (int)__popcll(m0);
        wcnt[wave][1] = (int)__popcll(m1);
        wcnt[wave][2] = (int)__popcll(m2);
    }
    __syncthreads();
    if (n < N_NODESC) {
        int basew = 0;
#pragma unroll
        for (int w = 0; w < 4; w++) if (w < wave) basew += wcnt[w][t];
        const unsigned long long mt = (t == 0) ? m0 : (t == 1) ? m1 : m2;
        const unsigned long long mlt = ((unsigned long long)1 << lane) - 1;
        const int p = bb[t * NPB + b] + basew + (int)__popcll(mt & mlt);
        origof[p] = n;
        newof[n] = p;
    }
}

// ---- Xp[newof[n]] = bf16(x[n]) ----
__global__ __launch_bounds__(256) void xb_kernel(
    const float* __restrict__ x, const int* __restrict__ newof, ushort* __restrict__ Xp)
{
    const int gid = blockIdx.x * 256 + threadIdx.x;
    if (gid >= N_NODESC * 32) return;
    const int n = gid >> 5, c = (gid & 31) * 4;
    const float4 v = *(const float4*)(x + (size_t)n * DD + c);
    ushort o[4] = {f2b(v.x), f2b(v.y), f2b(v.z), f2b(v.w)};
    const int p = newof[n];
    *(uint2*)(Xp + (size_t)p * DD + c) = *(uint2*)o;
}

// ---------------- CSR build (on permuted ids) ----------------
__global__ void deg_kernel(const int* __restrict__ dst, const int* __restrict__ newof,
                           int* __restrict__ deg) {
    const int e = blockIdx.x * 256 + threadIdx.x;
    if (e < N_EDGESC) atomicAdd(&deg[newof[dst[e]]], 1);
}

__global__ __launch_bounds__(1024) void scan_kernel(
    const int* __restrict__ deg, int* __restrict__ rowstart)
{
    __shared__ int part[1024];
    const int tid = threadIdx.x;
    const int per = 49;
    const int base = tid * per;
    int s = 0;
    for (int i = 0; i < per; i++) { int idx = base + i; if (idx < N_NODESC) s += deg[idx]; }
    part[tid] = s;
    __syncthreads();
    for (int off = 1; off < 1024; off <<= 1) {
        int v = (tid >= off) ? part[tid - off] : 0;
        __syncthreads();
        part[tid] += v;
        __syncthreads();
    }
    int run = (tid == 0) ? 0 : part[tid - 1];
    for (int i = 0; i < per; i++) {
        int idx = base + i;
        if (idx < N_NODESC) { rowstart[idx] = run; run += deg[idx]; }
    }
    if (tid == 1023) rowstart[N_NODESC] = part[1023];
}

__global__ void fill_kernel(const int* __restrict__ src, const int* __restrict__ dst,
                            const int* __restrict__ etype, const int* __restrict__ newof,
                            const int* __restrict__ rowstart,
                            int* __restrict__ cursor, int* __restrict__ edata) {
    const int e = blockIdx.x * 256 + threadIdx.x;
    if (e < N_EDGESC) {
        const int nd = newof[dst[e]];
        const int p = atomicAdd(&cursor[nd], 1);
        edata[rowstart[nd] + p] = newof[src[e]] | (etype[e] << 16);
    }
}

// ---------------- projection GEMM: Xp @ Wall[t] -> K8 | V8 | Qt8 (fp8) ----------------
#define LDP 40

__global__ __launch_bounds__(256) void proj_gemm(
    const ushort* __restrict__ Xp, const ushort* __restrict__ Wall,
    const int* __restrict__ tofs,
    unsigned char* __restrict__ K8, unsigned char* __restrict__ V8,
    unsigned char* __restrict__ Qt8)
{
    const int t = blockIdx.z;
    const int rs = tofs[t], re = tofs[t + 1];
    const int mBase = rs + blockIdx.x * 128;
    if (mBase >= re) return;
    const int nBase = blockIdx.y * 128;
    const ushort* Bt = Wall + (size_t)t * 896 * 128;

    __shared__ ushort As[128 * LDP];
    __shared__ ushort Bs[128 * LDP];
    const int tid = threadIdx.x;
    const int lane = tid & 63, wave = tid >> 6;
    const int mw = (wave >> 1) * 64, nw = (wave & 1) * 64;
    const int l15 = lane & 15, q8 = (lane >> 4) * 8;

    f32x4 acc[4][4];
#pragma unroll
    for (int i = 0; i < 4; i++)
#pragma unroll
        for (int j = 0; j < 4; j++) acc[i][j] = (f32x4){0.f, 0.f, 0.f, 0.f};

    const int r0 = tid >> 2, c0 = (tid & 3) * 8;
    int rA0 = mBase + r0;      if (rA0 >= N_NODESC) rA0 = N_NODESC - 1;
    int rA1 = mBase + r0 + 64; if (rA1 >= N_NODESC) rA1 = N_NODESC - 1;

    for (int kk = 0; kk < 128; kk += 32) {
        short8 a0 = *(const short8*)(Xp + (size_t)rA0 * DD + kk + c0);
        short8 a1 = *(const short8*)(Xp + (size_t)rA1 * DD + kk + c0);
        short8 b0 = *(const short8*)(Bt + (size_t)(nBase + r0) * 128 + kk + c0);
        short8 b1 = *(const short8*)(Bt + (size_t)(nBase + r0 + 64) * 128 + kk + c0);
        *(short8*)&As[r0 * LDP + c0] = a0;
        *(short8*)&As[(r0 + 64) * LDP + c0] = a1;
        *(short8*)&Bs[r0 * LDP + c0] = b0;
        *(short8*)&Bs[(r0 + 64) * LDP + c0] = b1;
        __syncthreads();
        short8 af[4], bf[4];
#pragma unroll
        for (int i = 0; i < 4; i++)
            af[i] = *(const short8*)&As[(mw + i * 16 + l15) * LDP + q8];
#pragma unroll
        for (int j = 0; j < 4; j++)
            bf[j] = *(const short8*)&Bs[(nw + j * 16 + l15) * LDP + q8];
#pragma unroll
        for (int i = 0; i < 4; i++)
#pragma unroll
            for (int j = 0; j < 4; j++)
                acc[i][j] = __builtin_amdgcn_mfma_f32_16x16x32_bf16(af[i], bf[j], acc[i][j], 0, 0, 0);
        __syncthreads();
    }

    const int rq = (lane >> 4) * 4;
#pragma unroll
    for (int i = 0; i < 4; i++) {
#pragma unroll
        for (int r = 0; r < 4; r++) {
            const int gm = mBase + mw + i * 16 + rq + r;
            if (gm >= re) continue;
#pragma unroll
            for (int j = 0; j < 4; j++) {
                const int gn = nBase + nw + j * 16 + l15;
                const float v = acc[i][j][r];
                const unsigned char b8 =
                    (unsigned char)(__builtin_amdgcn_cvt_pk_fp8_f32(v, v, 0, false) & 0xff);
                if (gn < 128)      K8[(size_t)gm * 128 + gn] = b8;
                else if (gn < 256) V8[(size_t)gm * 128 + (gn - 128)] = b8;
                else               Qt8[(size_t)gm * 640 + (gn - 256)] = b8;
            }
        }
    }
}

// ---------------- fused edge pass (fp8 gathers, permuted ids) ----------------
#define PROC(ed) { \
    const int s_ = (ed) & 0xffff; \
    const int et_ = (ed) >> 16; \
    const float k_ = __builtin_amdgcn_cvt_f32_fp8((int)K8[(size_t)s_ * 128 + f], 0); \
    const float v_ = __builtin_amdgcn_cvt_f32_fp8((int)V8[(size_t)s_ * 128 + f], 0); \
    const float qv_ = (et_ == 0) ? q0 : (et_ == 1) ? q1 : (et_ == 2) ? q2 : (et_ == 3) ? q3 : q4; \
    float p_ = qv_ * k_; \
    p_ += __shfl_xor(p_, 1); p_ += __shfl_xor(p_, 2); \
    p_ += __shfl_xor(p_, 4); p_ += __shfl_xor(p_, 8); \
    const float ex_ = __expf(p_ * (1.0f / 1024.0f)); \
    den += ex_; acc = fmaf(ex_, v_, acc); }

__global__ __launch_bounds__(128) void edgeagg_kernel(
    const int* __restrict__ rowstart, const int* __restrict__ edata,
    const unsigned char* __restrict__ Qt8,
    const unsigned char* __restrict__ K8, const unsigned char* __restrict__ V8,
    const int* __restrict__ origof, ushort* __restrict__ agg)
{
    const int n = blockIdx.x;
    const int f = threadIdx.x;
    const float q0 = __builtin_amdgcn_cvt_f32_fp8((int)Qt8[(size_t)n * 640 + 0 * 128 + f], 0);
    const float q1 = __builtin_amdgcn_cvt_f32_fp8((int)Qt8[(size_t)n * 640 + 1 * 128 + f], 0);
    const float q2 = __builtin_amdgcn_cvt_f32_fp8((int)Qt8[(size_t)n * 640 + 2 * 128 + f], 0);
    const float q3 = __builtin_amdgcn_cvt_f32_fp8((int)Qt8[(size_t)n * 640 + 3 * 128 + f], 0);
    const float q4 = __builtin_amdgcn_cvt_f32_fp8((int)Qt8[(size_t)n * 640 + 4 * 128 + f], 0);

    const int s0 = rowstart[n], s1 = rowstart[n + 1];
    float acc = 0.f, den = 0.f;
    int i = s0;
    for (; i + 3 < s1; i += 4) {
        const int e0 = edata[i], e1 = edata[i + 1], e2 = edata[i + 2], e3 = edata[i + 3];
        PROC(e0); PROC(e1); PROC(e2); PROC(e3);
    }
    for (; i < s1; i++) { const int e0 = edata[i]; PROC(e0); }
    // undo V scale (x4): 0.25
    agg[(size_t)origof[n] * DD + f] = f2b(0.25f * acc / (den + 1e-10f));
}

// ---- weight transposes to bf16 [N][K] for MFMA B-operand ----
__global__ __launch_bounds__(256) void convert_wt(
    const float* __restrict__ Wout, const float* __restrict__ W1, const float* __restrict__ W2,
    ushort* __restrict__ Woutt, ushort* __restrict__ W1t, ushort* __restrict__ W2t)
{
    const int gid = blockIdx.x * 256 + threadIdx.x;
    if (gid < 16384) {
        const int nn = gid >> 7, k = gid & 127;
        Woutt[gid] = f2b(Wout[k * 128 + nn]);
    } else if (gid < 16384 + 65536) {
        const int i = gid - 16384;
        const int nn = i >> 7, k = i & 127;
        W1t[i] = f2b(W1[k * 512 + nn]);
    } else if (gid < 16384 + 131072) {
        const int i = gid - 81920;
        const int nn = i >> 9, k = i & 511;
        W2t[i] = f2b(W2[k * 128 + nn]);
    }
}

// ---------------- MFMA bf16 GEMM 128x128 tile, BK=32, fused epilogues ----------------
// EPI 0: T = bf16 gelu(acc + bias)                (ffn1, grid.y = N/128)
// EPI 1: h1b = bf16 LN(acc + bias + residF)       (attn out)
// EPI 2: out = f32 LN(acc + bias + b2f(residB))   (ffn2)
template<int KT, int EPI>
__global__ __launch_bounds__(256) void mfma_gemm(
    const ushort* __restrict__ A, const ushort* __restrict__ Bt,
    const float* __restrict__ bias,
    const float* __restrict__ residF, const ushort* __restrict__ residB,
    const float* __restrict__ g, const float* __restrict__ b,
    float* __restrict__ outF, ushort* __restrict__ outB, int ldOut)
{
    __shared__ ushort As[128 * LDP];
    __shared__ ushort Bs[128 * LDP];
    __shared__ float red[2][2][128];
    const int tid = threadIdx.x;
    const int lane = tid & 63, wave = tid >> 6;
    const int mw = (wave >> 1) * 64, nw = (wave & 1) * 64;
    const int mBase = blockIdx.x * 128, nBase = blockIdx.y * 128;
    const int l15 = lane & 15, q8 = (lane >> 4) * 8;

    f32x4 acc[4][4];
#pragma unroll
    for (int i = 0; i < 4; i++)
#pragma unroll
        for (int j = 0; j < 4; j++) acc[i][j] = (f32x4){0.f, 0.f, 0.f, 0.f};

    const int r0 = tid >> 2;
    const int c0 = (tid & 3) * 8;

    for (int kk = 0; kk < KT; kk += 32) {
        const ushort* pa = A  + (size_t)(mBase + r0) * KT + kk + c0;
        const ushort* pb = Bt + (size_t)(nBase + r0) * KT + kk + c0;
        short8 a0 = *(const short8*)pa;
        short8 a1 = *(const short8*)(pa + (size_t)64 * KT);
        short8 b0 = *(const short8*)pb;
        short8 b1 = *(const short8*)(pb + (size_t)64 * KT);
        *(short8*)&As[r0 * LDP + c0] = a0;
        *(short8*)&As[(r0 + 64) * LDP + c0] = a1;
        *(short8*)&Bs[r0 * LDP + c0] = b0;
        *(short8*)&Bs[(r0 + 64) * LDP + c0] = b1;
        __syncthreads();

        short8 af[4], bf[4];
#pragma unroll
        for (int i = 0; i < 4; i++)
            af[i] = *(const short8*)&As[(mw + i * 16 + l15) * LDP + q8];
#pragma unroll
        for (int j = 0; j < 4; j++)
            bf[j] = *(const short8*)&Bs[(nw + j * 16 + l15) * LDP + q8];
#pragma unroll
        for (int i = 0; i < 4; i++)
#pragma unroll
            for (int j = 0; j < 4; j++)
                acc[i][j] = __builtin_amdgcn_mfma_f32_16x16x32_bf16(af[i], bf[j], acc[i][j], 0, 0, 0);
        __syncthreads();
    }

    const int rq = (lane >> 4) * 4;

    if (EPI == 0) {
#pragma unroll
        for (int i = 0; i < 4; i++) {
#pragma unroll
            for (int r = 0; r < 4; r++) {
                const int gm = mBase + mw + i * 16 + rq + r;
                if (gm >= N_NODESC) continue;
#pragma unroll
                for (int j = 0; j < 4; j++) {
                    const int gn = nBase + nw + j * 16 + l15;
                    float v = acc[i][j][r] + bias[gn];
                    v = 0.5f * v * (1.f + erff(v * 0.70710678118654752f));
                    outB[(size_t)gm * ldOut + gn] = f2b(v);
                }
            }
        }
    } else {
        float biasv[4], gv[4], bv[4];
#pragma unroll
        for (int j = 0; j < 4; j++) {
            const int gn = nw + j * 16 + l15;
            biasv[j] = bias[gn]; gv[j] = g[gn]; bv[j] = b[gn];
        }
#pragma unroll
        for (int i = 0; i < 4; i++) {
#pragma unroll
            for (int r = 0; r < 4; r++) {
                const int row = mw + i * 16 + rq + r;
                const int gm = mBase + row;
                float s = 0.f, ss = 0.f;
#pragma unroll
                for (int j = 0; j < 4; j++) {
                    const int gn = nw + j * 16 + l15;
                    float v = acc[i][j][r] + biasv[j];
                    if (EPI == 1) v += (gm < N_NODESC) ? residF[(size_t)gm * DD + gn] : 0.f;
                    else          v += (gm < N_NODESC) ? b2f(residB[(size_t)gm * DD + gn]) : 0.f;
                    acc[i][j][r] = v;
                    s += v; ss += v * v;
                }
                s  += __shfl_xor(s, 1);  s  += __shfl_xor(s, 2);  s  += __shfl_xor(s, 4);  s  += __shfl_xor(s, 8);
                ss += __shfl_xor(ss, 1); ss += __shfl_xor(ss, 2); ss += __shfl_xor(ss, 4); ss += __shfl_xor(ss, 8);
                if (l15 == 0) { red[0][nw >> 6][row] = s; red[1][nw >> 6][row] = ss; }
            }
        }
        __syncthreads();
#pragma unroll
        for (int i = 0; i < 4; i++) {
#pragma unroll
            for (int r = 0; r < 4; r++) {
                const int row = mw + i * 16 + rq + r;
                const int gm = mBase + row;
                if (gm >= N_NODESC) continue;
                const float s  = red[0][0][row] + red[0][1][row];
                const float ss = red[1][0][row] + red[1][1][row];
                const float mean = s * (1.f / 128.f);
                const float var  = ss * (1.f / 128.f) - mean * mean;
                const float rstd = rsqrtf(var + 1e-5f);
#pragma unroll
                for (int j = 0; j < 4; j++) {
                    const int gn = nw + j * 16 + l15;
                    const float o = (acc[i][j][r] - mean) * rstd * gv[j] + bv[j];
                    if (EPI == 1) outB[(size_t)gm * DD + gn] = f2b(o);
                    else          outF[(size_t)gm * DD + gn] = o;
                }
            }
        }
    }
}

extern "C" void kernel_launch(void* const* d_in, const int* in_sizes, int n_in,
                              void* d_out, int out_size, void* d_ws, size_t ws_size,
                              hipStream_t stream)
{
    const float* x     = (const float*)d_in[0];
    const int*   ei    = (const int*)d_in[1];
    const int*   etyp  = (const int*)d_in[2];
    const int*   ntype = (const int*)d_in[3];
    const float* Wq    = (const float*)d_in[4];
    const float* Wk    = (const float*)d_in[5];
    const float* Wv    = (const float*)d_in[6];
    const float* We    = (const float*)d_in[7];
    const float* mu    = (const float*)d_in[8];
    const float* Wout  = (const float*)d_in[9];
    const float* bout  = (const float*)d_in[10];
    const float* g1    = (const float*)d_in[11];
    const float* b1ln  = (const float*)d_in[12];
    const float* W1    = (const float*)d_in[13];
    const float* b1    = (const float*)d_in[14];
    const float* W2    = (const float*)d_in[15];
    const float* b2    = (const float*)d_in[16];
    const float* g2    = (const float*)d_in[17];
    const float* b2ln  = (const float*)d_in[18];
    float* out = (float*)d_out;

    char* ws = (char*)d_ws;
    unsigned char* K8    = (unsigned char*)(ws + K8_OFF);
    unsigned char* V8    = (unsigned char*)(ws + V8_OFF);
    unsigned char* Qt8   = (unsigned char*)(ws + QT8_OFF);
    ushort*        Xp    = (ushort*)(ws + XP_OFF);
    ushort*        T     = (ushort*)(ws + T_OFF);
    ushort*        agg   = (ushort*)(ws + AGG_OFF);
    ushort*        h1b   = (ushort*)(ws + H1B_OFF);
    ushort*        Woutt = (ushort*)(ws + WOUTT_OFF);
    ushort*        W1t   = (ushort*)(ws + W1T_OFF);
    ushort*        W2t   = (ushort*)(ws + W2T_OFF);
    float*         Wc    = (float*)(ws + WC_OFF);
    ushort*        Wall  = (ushort*)(ws + WALL_OFF);
    int*           edata = (int*)(ws + EDATA_OFF);
    int*           rows  = (int*)(ws + ROWS_OFF);
    int*           origof= (int*)(ws + ORIG_OFF);
    int*           newof = (int*)(ws + NEWOF_OFF);
    int*           deg   = (int*)(ws + DEG_OFF);
    int*           cur   = (int*)(ws + CUR_OFF);
    int*           tofs  = (int*)(ws + TOFS_OFF);
    int*           bh    = (int*)(ws + BH_OFF);
    int*           bb    = (int*)(ws + BB_OFF);

    const int* srcA = ei;
    const int* dstA = ei + N_EDGESC;

    // zero deg + cur (contiguous)
    (void)hipMemsetAsync(ws + DEG_OFF, 0, 400000, stream);

    convert_wt<<<576, 256, 0, stream>>>(Wout, W1, W2, Woutt, W1t, W2t);
    wc_kernel<<<dim3(N_ET, N_NT, HH), 256, 0, stream>>>(Wq, We, mu, Wc);
    wall_kernel<<<1344, 256, 0, stream>>>(Wk, Wv, Wc, Wall);

    // atomic-free counting sort by node type
    phist_kernel<<<NPB, 256, 0, stream>>>(ntype, bh);
    permscan_kernel<<<1, 640, 0, stream>>>(bh, bb, tofs);
    pscatter_kernel<<<NPB, 256, 0, stream>>>(ntype, bb, origof, newof);
    xb_kernel<<<6250, 256, 0, stream>>>(x, newof, Xp);

    deg_kernel<<<3125, 256, 0, stream>>>(dstA, newof, deg);
    scan_kernel<<<1, 1024, 0, stream>>>(deg, rows);
    fill_kernel<<<3125, 256, 0, stream>>>(srcA, dstA, etyp, newof, rows, cur, edata);

    proj_gemm<<<dim3(394, 7, 3), 256, 0, stream>>>(Xp, Wall, tofs, K8, V8, Qt8);
    edgeagg_kernel<<<N_NODESC, 128, 0, stream>>>(rows, edata, Qt8, K8, V8, origof, agg);

    // h1b = LN1(agg @ Wout + bout + x)  (bf16)
    mfma_gemm<128, 1><<<391, 256, 0, stream>>>(agg, Woutt, bout, x, nullptr, g1, b1ln, nullptr, h1b, 128);
    // T = gelu(h1b @ W1 + b1)  (bf16)
    mfma_gemm<128, 0><<<dim3(391, 4), 256, 0, stream>>>(h1b, W1t, b1, nullptr, nullptr, nullptr, nullptr, nullptr, T, 512);
    // out = LN2(T @ W2 + b2 + h1b)  (f32)
    mfma_gemm<512, 2><<<391, 256, 0, stream>>>(T, W2t, b2, nullptr, h1b, g2, b2ln, out, nullptr, 128);
}